// Round 1
// baseline (160.871 us; speedup 1.0000x reference)
//
#include <hip/hip_runtime.h>

// Per-clause softmax-attention pooling — two-phase (scores, then weighted sum).
// B=64, T=512, D=768, C=31 -> 32 segments/batch, 2048 segments total.
//
// Previous version used a per-token ONLINE softmax: each token's update was a
// serial chain (6-shfl butterfly -> exp -> rescale) with only ~4-8 tokens per
// wave, so the chain latency dominated (est ~2x off the BW roofline).
//
// This version removes the chain:
//   Phase 1: each wave computes scores for tokens t = wave, wave+4, ...
//            (dot + 6-shfl reduce). Iterations are INDEPENDENT -> the shfl
//            chains pipeline across tokens. Scores -> LDS.
//   Phase 2: one barrier; every thread redundantly computes M = max(s),
//            S = sum exp(s-M) from the <=31 LDS scores (broadcast reads).
//            b5 bias is dropped: softmax is shift-invariant.
//   Phase 3: acc += exp(s[t]-M)/S * row[t] with known weights: no cross-lane
//            ops, no serial chain; loads independent. Rows were read ~1-2 us
//            earlier -> served by L2/L3 (input 100 MB < 256 MB LLC), so HBM
//            traffic stays ~1x read of hidden.
//   Merge:   plain 4-wave sum via LDS (weights already normalized).

#define B_ 64
#define T_ 512
#define D_ 768
#define C_ 31
#define NSEG 32  // C+1

__global__ __launch_bounds__(256) void seg_softmax_pool_2p(
    const float* __restrict__ hidden,    // [B, T, D]
    const int*   __restrict__ clause_b,  // [B, C]
    const float* __restrict__ w5,        // [D]
    const float* __restrict__ b5,        // [1] (unused: cancels in softmax)
    float*       __restrict__ out)       // [B, NSEG, D]
{
    const int tid  = threadIdx.x;
    const int wave = tid >> 6;
    const int lane = tid & 63;
    const int seg  = blockIdx.x;              // 0..2047
    const int b    = seg >> 5;                // / NSEG
    const int j    = seg & 31;                // % NSEG

    const int start = (j == 0)  ? 0  : clause_b[b * C_ + j - 1];
    const int end   = (j == C_) ? T_ : clause_b[b * C_ + j];
    const int L     = end - start;            // [2, 30] by construction

    // Lane owns dims d = c*256 + 4*lane + {0..3}, c in {0,1,2}.
    const int doff = 4 * lane;
    const float4 w0 = *(const float4*)(w5 + doff);
    const float4 w1 = *(const float4*)(w5 + doff + 256);
    const float4 w2 = *(const float4*)(w5 + doff + 512);

    const float* hseg = hidden + ((size_t)b * T_ + start) * D_ + doff;

    __shared__ float s_s[NSEG];       // segment scores
    __shared__ float s_acc[4][D_];    // 12 KB merge buffer

    // ---- Phase 1: scores (independent iterations -> pipelined reduces) ----
    #pragma unroll 2
    for (int t = wave; t < L; t += 4) {
        const float* p = hseg + (size_t)t * D_;
        const float4 c0 = *(const float4*)(p);
        const float4 c1 = *(const float4*)(p + 256);
        const float4 c2 = *(const float4*)(p + 512);
        float s = c0.x * w0.x + c0.y * w0.y + c0.z * w0.z + c0.w * w0.w
                + c1.x * w1.x + c1.y * w1.y + c1.z * w1.z + c1.w * w1.w
                + c2.x * w2.x + c2.y * w2.y + c2.z * w2.z + c2.w * w2.w;
        #pragma unroll
        for (int off = 32; off > 0; off >>= 1)
            s += __shfl_xor(s, off, 64);
        if (lane == 0) s_s[t] = s;
    }
    __syncthreads();

    // ---- Phase 2: every thread computes M and 1/S (broadcast LDS reads) ----
    float M = -INFINITY;
    for (int t = 0; t < L; ++t) M = fmaxf(M, s_s[t]);
    float S = 0.0f;
    for (int t = 0; t < L; ++t) S += __expf(s_s[t] - M);
    const float invS = 1.0f / S;

    // ---- Phase 3: weighted accumulate, chain-free (weights known) ----
    float4 a0 = make_float4(0.f, 0.f, 0.f, 0.f);
    float4 a1 = a0, a2 = a0;
    #pragma unroll 2
    for (int t = wave; t < L; t += 4) {
        const float wgt = __expf(s_s[t] - M) * invS;
        const float* p = hseg + (size_t)t * D_;
        const float4 c0 = *(const float4*)(p);
        const float4 c1 = *(const float4*)(p + 256);
        const float4 c2 = *(const float4*)(p + 512);
        a0.x = fmaf(wgt, c0.x, a0.x);  a0.y = fmaf(wgt, c0.y, a0.y);
        a0.z = fmaf(wgt, c0.z, a0.z);  a0.w = fmaf(wgt, c0.w, a0.w);
        a1.x = fmaf(wgt, c1.x, a1.x);  a1.y = fmaf(wgt, c1.y, a1.y);
        a1.z = fmaf(wgt, c1.z, a1.z);  a1.w = fmaf(wgt, c1.w, a1.w);
        a2.x = fmaf(wgt, c2.x, a2.x);  a2.y = fmaf(wgt, c2.y, a2.y);
        a2.z = fmaf(wgt, c2.z, a2.z);  a2.w = fmaf(wgt, c2.w, a2.w);
    }

    // ---- Merge across 4 waves (plain sum; weights already normalized) ----
    float* dst = &s_acc[wave][doff];
    *(float4*)(dst)       = a0;
    *(float4*)(dst + 256) = a1;
    *(float4*)(dst + 512) = a2;
    __syncthreads();

    // Each thread owns dims d = tid, tid+256, tid+512.
    float* op = out + ((size_t)b * NSEG + j) * D_;
    #pragma unroll
    for (int k = 0; k < 3; ++k) {
        const int d = tid + k * 256;
        op[d] = s_acc[0][d] + s_acc[1][d] + s_acc[2][d] + s_acc[3][d];
    }
}

extern "C" void kernel_launch(void* const* d_in, const int* in_sizes, int n_in,
                              void* d_out, int out_size, void* d_ws, size_t ws_size,
                              hipStream_t stream) {
    const float* hidden   = (const float*)d_in[0];
    const int*   clause_b = (const int*)d_in[1];
    const float* w5       = (const float*)d_in[2];
    const float* b5       = (const float*)d_in[3];
    float*       out      = (float*)d_out;

    // One block per segment: 2048 blocks x 256 threads = 8192 waves.
    seg_softmax_pool_2p<<<B_ * NSEG, 256, 0, stream>>>(hidden, clause_b, w5, b5, out);
}

// Round 2
// 155.208 us; speedup vs baseline: 1.0365x; 1.0365x over previous
//
#include <hip/hip_runtime.h>

// Per-clause softmax-attention pooling — single-pass online softmax,
// occupancy-forced (8 blocks/CU so the whole 2048-block grid is co-resident).
// B=64, T=512, D=768, C=31 -> 32 segments/batch, 2048 segments total.
//
// Round-1 post-mortem: removing the per-token serial chain (two-phase) made
// things WORSE (+5.8us) because phase 3 re-read segment rows through L3.
// => chain stalls are already hidden by TLP; single-pass is structurally right.
// Remaining theory: round-0 used ~70-85 VGPRs (w+cur+next+acc float4s) ->
// 6 waves/SIMD -> 6 blocks/CU < the 8 needed for one residency round; the
// 512-block second round + L-imbalance is the ~2x gap vs the 17us BW roofline.
//
// This version: __launch_bounds__(256, 8) forces VGPR<=64 (8 blocks/CU).
// Register diet: no explicit prefetch buffer; instead 2 tokens/iteration with
// both rows' loads hoisted above the (serial) online update - loads are
// independent of the m/denom chain, so they issue back-to-back and the two
// shfl butterflies interleave. Bias dropped (softmax shift-invariant).

#define B_ 64
#define T_ 512
#define D_ 768
#define C_ 31
#define NSEG 32  // C+1

__global__ __launch_bounds__(256, 8) void seg_softmax_pool_v3(
    const float* __restrict__ hidden,    // [B, T, D]
    const int*   __restrict__ clause_b,  // [B, C]
    const float* __restrict__ w5,        // [D]
    const float* __restrict__ b5,        // [1] (unused: cancels in softmax)
    float*       __restrict__ out)       // [B, NSEG, D]
{
    const int tid  = threadIdx.x;
    const int wave = tid >> 6;
    const int lane = tid & 63;
    const int seg  = blockIdx.x;              // 0..2047
    const int b    = seg >> 5;                // / NSEG
    const int j    = seg & 31;                // % NSEG

    const int start = (j == 0)  ? 0  : clause_b[b * C_ + j - 1];
    const int end   = (j == C_) ? T_ : clause_b[b * C_ + j];
    const int L     = end - start;            // [2, 30] by construction

    // Lane owns dims d = c*256 + 4*lane + {0..3}, c in {0,1,2}.
    const int doff = 4 * lane;
    const float4 w0 = *(const float4*)(w5 + doff);
    const float4 w1 = *(const float4*)(w5 + doff + 256);
    const float4 w2 = *(const float4*)(w5 + doff + 512);

    const float* hseg = hidden + ((size_t)b * T_ + start) * D_ + doff;

    float4 a0 = make_float4(0.f, 0.f, 0.f, 0.f);
    float4 a1 = a0, a2 = a0;
    float m = -INFINITY, denom = 0.0f;

    // Two tokens per iteration: t and t+4 (this wave's consecutive tokens).
    int t = wave;
    for (; t + 4 < L; t += 8) {
        const float* p0 = hseg + (size_t)t * D_;
        const float* p1 = p0 + 4 * (size_t)D_;
        // All six loads are independent of the online chain -> issue together.
        const float4 x0 = *(const float4*)(p0);
        const float4 x1 = *(const float4*)(p0 + 256);
        const float4 x2 = *(const float4*)(p0 + 512);
        const float4 y0 = *(const float4*)(p1);
        const float4 y1 = *(const float4*)(p1 + 256);
        const float4 y2 = *(const float4*)(p1 + 512);

        float sx = x0.x * w0.x;  float sy = y0.x * w0.x;
        sx = fmaf(x0.y, w0.y, sx);  sy = fmaf(y0.y, w0.y, sy);
        sx = fmaf(x0.z, w0.z, sx);  sy = fmaf(y0.z, w0.z, sy);
        sx = fmaf(x0.w, w0.w, sx);  sy = fmaf(y0.w, w0.w, sy);
        sx = fmaf(x1.x, w1.x, sx);  sy = fmaf(y1.x, w1.x, sy);
        sx = fmaf(x1.y, w1.y, sx);  sy = fmaf(y1.y, w1.y, sy);
        sx = fmaf(x1.z, w1.z, sx);  sy = fmaf(y1.z, w1.z, sy);
        sx = fmaf(x1.w, w1.w, sx);  sy = fmaf(y1.w, w1.w, sy);
        sx = fmaf(x2.x, w2.x, sx);  sy = fmaf(y2.x, w2.x, sy);
        sx = fmaf(x2.y, w2.y, sx);  sy = fmaf(y2.y, w2.y, sy);
        sx = fmaf(x2.z, w2.z, sx);  sy = fmaf(y2.z, w2.z, sy);
        sx = fmaf(x2.w, w2.w, sx);  sy = fmaf(y2.w, w2.w, sy);

        // Two interleaved butterflies (independent -> DS pipe stays busy).
        #pragma unroll
        for (int off = 32; off > 0; off >>= 1) {
            sx += __shfl_xor(sx, off, 64);
            sy += __shfl_xor(sy, off, 64);
        }

        // Online update, token t.
        {
            const float mn    = fmaxf(m, sx);
            const float scale = __expf(m - mn);   // 0 on first token
            const float e     = __expf(sx - mn);
            denom = denom * scale + e;
            a0.x = fmaf(a0.x, scale, e * x0.x);  a0.y = fmaf(a0.y, scale, e * x0.y);
            a0.z = fmaf(a0.z, scale, e * x0.z);  a0.w = fmaf(a0.w, scale, e * x0.w);
            a1.x = fmaf(a1.x, scale, e * x1.x);  a1.y = fmaf(a1.y, scale, e * x1.y);
            a1.z = fmaf(a1.z, scale, e * x1.z);  a1.w = fmaf(a1.w, scale, e * x1.w);
            a2.x = fmaf(a2.x, scale, e * x2.x);  a2.y = fmaf(a2.y, scale, e * x2.y);
            a2.z = fmaf(a2.z, scale, e * x2.z);  a2.w = fmaf(a2.w, scale, e * x2.w);
            m = mn;
        }
        // Online update, token t+4.
        {
            const float mn    = fmaxf(m, sy);
            const float scale = __expf(m - mn);
            const float e     = __expf(sy - mn);
            denom = denom * scale + e;
            a0.x = fmaf(a0.x, scale, e * y0.x);  a0.y = fmaf(a0.y, scale, e * y0.y);
            a0.z = fmaf(a0.z, scale, e * y0.z);  a0.w = fmaf(a0.w, scale, e * y0.w);
            a1.x = fmaf(a1.x, scale, e * y1.x);  a1.y = fmaf(a1.y, scale, e * y1.y);
            a1.z = fmaf(a1.z, scale, e * y1.z);  a1.w = fmaf(a1.w, scale, e * y1.w);
            a2.x = fmaf(a2.x, scale, e * y2.x);  a2.y = fmaf(a2.y, scale, e * y2.y);
            a2.z = fmaf(a2.z, scale, e * y2.z);  a2.w = fmaf(a2.w, scale, e * y2.w);
            m = mn;
        }
    }
    // Tail: at most one remaining token for this wave.
    if (t < L) {
        const float* p0 = hseg + (size_t)t * D_;
        const float4 x0 = *(const float4*)(p0);
        const float4 x1 = *(const float4*)(p0 + 256);
        const float4 x2 = *(const float4*)(p0 + 512);
        float sx = x0.x * w0.x;
        sx = fmaf(x0.y, w0.y, sx);  sx = fmaf(x0.z, w0.z, sx);  sx = fmaf(x0.w, w0.w, sx);
        sx = fmaf(x1.x, w1.x, sx);  sx = fmaf(x1.y, w1.y, sx);
        sx = fmaf(x1.z, w1.z, sx);  sx = fmaf(x1.w, w1.w, sx);
        sx = fmaf(x2.x, w2.x, sx);  sx = fmaf(x2.y, w2.y, sx);
        sx = fmaf(x2.z, w2.z, sx);  sx = fmaf(x2.w, w2.w, sx);
        #pragma unroll
        for (int off = 32; off > 0; off >>= 1)
            sx += __shfl_xor(sx, off, 64);
        const float mn    = fmaxf(m, sx);
        const float scale = __expf(m - mn);
        const float e     = __expf(sx - mn);
        denom = denom * scale + e;
        a0.x = fmaf(a0.x, scale, e * x0.x);  a0.y = fmaf(a0.y, scale, e * x0.y);
        a0.z = fmaf(a0.z, scale, e * x0.z);  a0.w = fmaf(a0.w, scale, e * x0.w);
        a1.x = fmaf(a1.x, scale, e * x1.x);  a1.y = fmaf(a1.y, scale, e * x1.y);
        a1.z = fmaf(a1.z, scale, e * x1.z);  a1.w = fmaf(a1.w, scale, e * x1.w);
        a2.x = fmaf(a2.x, scale, e * x2.x);  a2.y = fmaf(a2.y, scale, e * x2.y);
        a2.z = fmaf(a2.z, scale, e * x2.z);  a2.w = fmaf(a2.w, scale, e * x2.w);
        m = mn;
    }

    // ---- Cross-wave merge (flash-attention rescale) ----
    __shared__ float s_acc[4][D_];   // 12 KB
    __shared__ float s_m[4], s_d[4];

    if (lane == 0) { s_m[wave] = m; s_d[wave] = denom; }
    __syncthreads();

    const float M = fmaxf(fmaxf(s_m[0], s_m[1]), fmaxf(s_m[2], s_m[3]));
    const float Tden = s_d[0] * __expf(s_m[0] - M) + s_d[1] * __expf(s_m[1] - M)
                     + s_d[2] * __expf(s_m[2] - M) + s_d[3] * __expf(s_m[3] - M);
    const float myscale = __expf(m - M);      // 0 for token-less waves (m=-inf)

    float* dst = &s_acc[wave][doff];
    *(float4*)(dst)       = make_float4(a0.x * myscale, a0.y * myscale, a0.z * myscale, a0.w * myscale);
    *(float4*)(dst + 256) = make_float4(a1.x * myscale, a1.y * myscale, a1.z * myscale, a1.w * myscale);
    *(float4*)(dst + 512) = make_float4(a2.x * myscale, a2.y * myscale, a2.z * myscale, a2.w * myscale);
    __syncthreads();

    // Each thread owns dims d = tid, tid+256, tid+512.
    const float inv = 1.0f / Tden;
    float* op = out + ((size_t)b * NSEG + j) * D_;
    #pragma unroll
    for (int k = 0; k < 3; ++k) {
        const int d = tid + k * 256;
        const float v = s_acc[0][d] + s_acc[1][d] + s_acc[2][d] + s_acc[3][d];
        op[d] = v * inv;
    }
}

extern "C" void kernel_launch(void* const* d_in, const int* in_sizes, int n_in,
                              void* d_out, int out_size, void* d_ws, size_t ws_size,
                              hipStream_t stream) {
    const float* hidden   = (const float*)d_in[0];
    const int*   clause_b = (const int*)d_in[1];
    const float* w5       = (const float*)d_in[2];
    const float* b5       = (const float*)d_in[3];
    float*       out      = (float*)d_out;

    // One block per segment: 2048 blocks x 256 threads = 8192 waves.
    // 8 blocks/CU (forced by launch_bounds) -> entire grid co-resident.
    seg_softmax_pool_v3<<<B_ * NSEG, 256, 0, stream>>>(hidden, clause_b, w5, b5, out);
}